// Round 2
// baseline (2729.319 us; speedup 1.0000x reference)
//
#include <hip/hip_runtime.h>

// Shapes (compile-time): B=256, P=196, ENC=2048, WORD=512, ATT=512
#define B_   256
#define P_   196
#define E_   2048
#define WD_  512
#define A_   512
#define M_   (B_ * P_)   // 50176, divisible by 32

// ---------------------------------------------------------------------------
// Kernel 1: att_dec[b][a] = dot(decoder_out[b,:], W_dec[:,a]) + b_dec[a]
// grid = B_, block = 512 (one thread per a)
// ---------------------------------------------------------------------------
__global__ __launch_bounds__(512) void k_att_dec(const float* __restrict__ dec,
                                                 const float* __restrict__ Wd,
                                                 const float* __restrict__ bd,
                                                 float* __restrict__ att_dec) {
    int b = blockIdx.x, a = threadIdx.x;
    __shared__ float sd[WD_];
    sd[a] = dec[b * WD_ + a];
    __syncthreads();
    float acc = bd[a];
#pragma unroll 8
    for (int e = 0; e < WD_; ++e)
        acc = fmaf(sd[e], Wd[e * A_ + a], acc);
    att_dec[b * A_ + a] = acc;
}

// ---------------------------------------------------------------------------
// Kernel 2: fused logits.
//   att[m] = sum_a relu( enc_row[m] . W_enc[:,a] + b_enc[a] + att_dec[b][a] ) * W_fin[a]
// (b_fin omitted: softmax-invariant constant)
// Tiling: block = 256 threads, M-tile 32 rows x all 512 cols, K staged 16 at a time.
// Thread (rg = t>>6 in [0,4), cg = t&63): rows rg*8+i, cols j*64+cg  -> acc[8][8].
// Wave == rg group, so the epilogue col-reduction is a single 64-lane shfl tree.
// LDS: sA 32x17 fp32 (pad+1), sB 16x512 fp32 = ~35 KB -> 4 blocks/CU.
// sA reads in the inner loop are wave-broadcast (same addr across lanes, free);
// sB reads are lane-consecutive (conflict-free).
// ---------------------------------------------------------------------------
__global__ __launch_bounds__(256) void k_logits(const float* __restrict__ enc,
                                                const float* __restrict__ We,
                                                const float* __restrict__ be,
                                                const float* __restrict__ Wf,
                                                const float* __restrict__ att_dec,
                                                float* __restrict__ att) {
    __shared__ float sA[32][17];
    __shared__ float sB[16][512];

    const int t  = threadIdx.x;
    const int rg = t >> 6;         // 0..3 == wave id
    const int cg = t & 63;         // lane
    const int m0 = blockIdx.x * 32;

    float acc[8][8];
#pragma unroll
    for (int i = 0; i < 8; ++i)
#pragma unroll
        for (int j = 0; j < 8; ++j) acc[i][j] = 0.f;

    // staging assignments
    const int ar  = t >> 3;            // 0..31 (A row)
    const int ac  = (t & 7) << 1;      // 0,2,...,14 (A col pair)
    const int bkr = t >> 4;            // 0..15 (B k-row)
    const int bcs = (t & 15) << 5;     // 0..480 step 32 (B col segment, 32 floats)

    const float* aptr = enc + (size_t)(m0 + ar) * E_ + ac;

    for (int k0 = 0; k0 < E_; k0 += 16) {
        // --- stage A tile (32 x 16 fp32) : 2 elems/thread (float2, 8 B)
        float2 fa = *(const float2*)(aptr + k0);
        sA[ar][ac] = fa.x; sA[ar][ac + 1] = fa.y;

        // --- stage B tile (16 x 512 fp32) : 32 elems/thread (8 x float4)
        const float4* bsrc = (const float4*)(We + (size_t)(k0 + bkr) * A_ + bcs);
#pragma unroll
        for (int i = 0; i < 8; ++i) {
            float4 q = bsrc[i];
            float* d = &sB[bkr][bcs + i * 4];
            d[0] = q.x; d[1] = q.y; d[2] = q.z; d[3] = q.w;
        }
        __syncthreads();

#pragma unroll
        for (int kt = 0; kt < 16; ++kt) {
            float av[8];
#pragma unroll
            for (int i = 0; i < 8; ++i) av[i] = sA[rg * 8 + i][kt];
#pragma unroll
            for (int j = 0; j < 8; ++j) {
                float bv = sB[kt][j * 64 + cg];
#pragma unroll
                for (int i = 0; i < 8; ++i) acc[i][j] = fmaf(av[i], bv, acc[i][j]);
            }
        }
        __syncthreads();
    }

    // --- epilogue: relu(acc + b_enc + att_dec) . W_fin, reduce over a ---
    float wf[8], bev[8];
#pragma unroll
    for (int j = 0; j < 8; ++j) {
        wf[j]  = Wf[j * 64 + cg];
        bev[j] = be[j * 64 + cg];
    }
#pragma unroll
    for (int i = 0; i < 8; ++i) {
        int m = m0 + rg * 8 + i;
        int b = m / P_;
        const float* adp = att_dec + b * A_;
        float s = 0.f;
#pragma unroll
        for (int j = 0; j < 8; ++j) {
            float h = acc[i][j] + bev[j] + adp[j * 64 + cg];
            h = fmaxf(h, 0.f);
            s = fmaf(h, wf[j], s);
        }
#pragma unroll
        for (int off = 32; off > 0; off >>= 1)
            s += __shfl_down(s, off, 64);
        if (cg == 0) att[m] = s;
    }
}

// ---------------------------------------------------------------------------
// Kernel 3: per-batch softmax over P, then out[b][e] = sum_p w[p]*enc[b][p][e]
// grid = B_, block = 256; thread handles 8 contiguous e (2 x float4 loads).
// ---------------------------------------------------------------------------
__global__ __launch_bounds__(256) void k_out(const float* __restrict__ enc,
                                             const float* __restrict__ att,
                                             float* __restrict__ out) {
    int b = blockIdx.x, t = threadIdx.x;
    __shared__ float sw[P_];
    __shared__ float red[8];

    float v = (t < P_) ? att[b * P_ + t] : -1e30f;
    float m = v;
#pragma unroll
    for (int off = 32; off > 0; off >>= 1)
        m = fmaxf(m, __shfl_down(m, off, 64));
    int wid = t >> 6;
    if ((t & 63) == 0) red[wid] = m;
    __syncthreads();
    m = fmaxf(fmaxf(red[0], red[1]), fmaxf(red[2], red[3]));

    float ev = (t < P_) ? __expf(v - m) : 0.f;
    float s = ev;
#pragma unroll
    for (int off = 32; off > 0; off >>= 1)
        s += __shfl_down(s, off, 64);
    if ((t & 63) == 0) red[4 + wid] = s;
    __syncthreads();
    s = red[4] + red[5] + red[6] + red[7];
    if (t < P_) sw[t] = ev / s;
    __syncthreads();

    float accv[8];
#pragma unroll
    for (int j = 0; j < 8; ++j) accv[j] = 0.f;

    const float4* ep = (const float4*)(enc + (size_t)b * P_ * E_ + t * 8);
    // stride between p rows: E_/4 = 512 float4s
    for (int p = 0; p < P_; ++p) {
        float4 q0 = ep[(size_t)p * (E_ / 4)];
        float4 q1 = ep[(size_t)p * (E_ / 4) + 1];
        float w = sw[p];
        accv[0] = fmaf(w, q0.x, accv[0]);
        accv[1] = fmaf(w, q0.y, accv[1]);
        accv[2] = fmaf(w, q0.z, accv[2]);
        accv[3] = fmaf(w, q0.w, accv[3]);
        accv[4] = fmaf(w, q1.x, accv[4]);
        accv[5] = fmaf(w, q1.y, accv[5]);
        accv[6] = fmaf(w, q1.z, accv[6]);
        accv[7] = fmaf(w, q1.w, accv[7]);
    }
    float* op = out + (size_t)b * E_ + t * 8;
#pragma unroll
    for (int j = 0; j < 8; ++j) op[j] = accv[j];
}

// ---------------------------------------------------------------------------
extern "C" void kernel_launch(void* const* d_in, const int* in_sizes, int n_in,
                              void* d_out, int out_size, void* d_ws, size_t ws_size,
                              hipStream_t stream) {
    const float* enc   = (const float*)d_in[0];  // [B,P,E]  fp32
    const float* dec   = (const float*)d_in[1];  // [B,WD]   fp32
    const float* W_enc = (const float*)d_in[2];  // [E,A]    fp32
    const float* b_enc = (const float*)d_in[3];  // [A]      fp32
    const float* W_dec = (const float*)d_in[4];  // [WD,A]   fp32
    const float* b_dec = (const float*)d_in[5];  // [A]      fp32
    const float* W_fin = (const float*)d_in[6];  // [A]      fp32
    // d_in[7] = b_fin: softmax-invariant constant -> unused.

    float* att_dec = (float*)d_ws;           // B_*A_   fp32 (512 KB)
    float* att     = att_dec + B_ * A_;      // B_*P_   fp32 (~200 KB)

    k_att_dec<<<B_, 512, 0, stream>>>(dec, W_dec, b_dec, att_dec);
    k_logits<<<M_ / 32, 256, 0, stream>>>(enc, W_enc, b_enc, W_fin, att_dec, att);
    k_out<<<B_, 256, 0, stream>>>(enc, att, (float*)d_out);
}

// Round 3
// 893.582 us; speedup vs baseline: 3.0544x; 3.0544x over previous
//
#include <hip/hip_runtime.h>

// Shapes: B=256, P=196, ENC=2048, WORD=512, ATT=512
#define B_   256
#define P_   196
#define E_   2048
#define WD_  512
#define A_   512
#define M_   (B_ * P_)   // 50176 = 784 * 64

typedef __bf16 bf16x8 __attribute__((ext_vector_type(8)));
typedef float  f32x4  __attribute__((ext_vector_type(4)));

using u16 = unsigned short;
using u32 = unsigned int;

__device__ inline u16 f2bf(float f) {  // RNE
    u32 u; __builtin_memcpy(&u, &f, 4);
    u32 lsb = (u >> 16) & 1u; u += 0x7FFFu + lsb; return (u16)(u >> 16);
}

__device__ inline void gload_lds16(const void* g, void* lds) {
    __builtin_amdgcn_global_load_lds(
        (const __attribute__((address_space(1))) u32*)g,
        (__attribute__((address_space(3))) u32*)lds, 16, 0, 0);
}

// ---------------------------------------------------------------------------
// k_prep: W_enc fp32 [E][A] -> Wt bf16 [A][E] (transpose + convert).
// grid (E/32, A/32) = (64,16), block 256 (tx=0..31, ty=0..7).
// ---------------------------------------------------------------------------
__global__ __launch_bounds__(256) void k_prep(const float* __restrict__ We,
                                              u16* __restrict__ Wt) {
    __shared__ float tile[32][33];
    const int tx = threadIdx.x & 31, ty = threadIdx.x >> 5;
    const int k0 = blockIdx.x * 32, n0 = blockIdx.y * 32;
#pragma unroll
    for (int i = 0; i < 4; ++i)
        tile[ty + i * 8][tx] = We[(size_t)(k0 + ty + i * 8) * A_ + n0 + tx];
    __syncthreads();
#pragma unroll
    for (int i = 0; i < 4; ++i)
        Wt[(size_t)(n0 + ty + i * 8) * E_ + k0 + tx] = f2bf(tile[tx][ty + i * 8]);
}

// ---------------------------------------------------------------------------
// k_att_dec: att_dec[b][a] = dot(dec[b,:], Wd[:,a]) + bd[a]
// ---------------------------------------------------------------------------
__global__ __launch_bounds__(512) void k_att_dec(const float* __restrict__ dec,
                                                 const float* __restrict__ Wd,
                                                 const float* __restrict__ bd,
                                                 float* __restrict__ att_dec) {
    int b = blockIdx.x, a = threadIdx.x;
    __shared__ float sd[WD_];
    sd[a] = dec[b * WD_ + a];
    __syncthreads();
    float acc = bd[a];
#pragma unroll 8
    for (int e = 0; e < WD_; ++e)
        acc = fmaf(sd[e], Wd[e * A_ + a], acc);
    att_dec[b * A_ + a] = acc;
}

// ---------------------------------------------------------------------------
// k_logits (MFMA): att[m] = sum_n relu(enc[m,:].W_enc[:,n] + be[n] + att_dec[b][n]) * Wf[n]
// Block: 256 thr = 4 waves. M-tile 64 x N=512, BK=64, mfma_f32_16x16x32_bf16.
// Wave w: rows 0..63 (all) x cols [w*128, w*128+128) -> acc[4 rt][8 ct] of f32x4.
// LDS in fragment order: sA[(rt*2+s)*64 + lane] (8 KB), sB[(ctg*2+s)*64 + lane] (64 KB);
// all LDS traffic is linear lane*16 -> conflict-free. A: fp32->bf16 on the fly;
// B: global_load_lds width-16 DMA from pre-transposed Wt.
// ---------------------------------------------------------------------------
__global__ __launch_bounds__(256, 2) void k_logits(
        const float* __restrict__ enc, const u16* __restrict__ Wt,
        const float* __restrict__ be, const float* __restrict__ Wf,
        const float* __restrict__ att_dec, float* __restrict__ att) {
    __shared__ bf16x8 sA[4 * 2 * 64];    // 8 KB
    __shared__ bf16x8 sB[32 * 2 * 64];   // 64 KB
    __shared__ float  sred[4][64];       // 1 KB

    const int t   = threadIdx.x;
    const int w   = t >> 6;     // wave 0..3
    const int L   = t & 63;
    const int l15 = L & 15;
    const int q   = L >> 4;     // 0..3
    const int m0  = blockIdx.x * 64;

    const f32x4 zero = {0.f, 0.f, 0.f, 0.f};
    f32x4 acc[4][8];
#pragma unroll
    for (int rt = 0; rt < 4; ++rt)
#pragma unroll
        for (int ct = 0; ct < 8; ++ct) acc[rt][ct] = zero;

    // per-lane invariant bases
    const float* ag = enc + (size_t)(m0 + w * 16 + l15) * E_ + q * 8;
    const u16*   bg = Wt + (size_t)(w * 8 * 16 + l15) * E_ + q * 8;

    for (int k0 = 0; k0 < E_; k0 += 64) {
        // --- stage A: wave w stages row-tile rt=w, fragment order ---
#pragma unroll
        for (int s = 0; s < 2; ++s) {
            const float* ap = ag + k0 + s * 32;
            float4 f0 = *(const float4*)(ap);
            float4 f1 = *(const float4*)(ap + 4);
            u16 h[8];
            h[0] = f2bf(f0.x); h[1] = f2bf(f0.y); h[2] = f2bf(f0.z); h[3] = f2bf(f0.w);
            h[4] = f2bf(f1.x); h[5] = f2bf(f1.y); h[6] = f2bf(f1.z); h[7] = f2bf(f1.w);
            bf16x8 v; __builtin_memcpy(&v, h, 16);
            sA[(w * 2 + s) * 64 + L] = v;
        }
        // --- stage B: wave w stages its 8 col-tiles x 2 k-steps via DMA ---
#pragma unroll
        for (int i = 0; i < 16; ++i) {
            int ctl = i >> 1, s = i & 1;
            const u16* gp = bg + (size_t)ctl * 16 * E_ + k0 + s * 32;
            gload_lds16(gp, (void*)&sB[((w * 8 + ctl) * 2 + s) * 64]);
        }
        __syncthreads();

        // --- compute: 64 MFMA per wave ---
#pragma unroll
        for (int s = 0; s < 2; ++s) {
            bf16x8 af[4], bfr[8];
#pragma unroll
            for (int rt = 0; rt < 4; ++rt) af[rt] = sA[(rt * 2 + s) * 64 + L];
#pragma unroll
            for (int ct = 0; ct < 8; ++ct) bfr[ct] = sB[((w * 8 + ct) * 2 + s) * 64 + L];
#pragma unroll
            for (int ct = 0; ct < 8; ++ct)
#pragma unroll
                for (int rt = 0; rt < 4; ++rt)
                    acc[rt][ct] = __builtin_amdgcn_mfma_f32_16x16x32_bf16(
                        af[rt], bfr[ct], acc[rt][ct], 0, 0, 0);
        }
        __syncthreads();
    }

    // --- epilogue: relu(acc + be + att_dec) . Wf, reduce n ---
    float wf[8], bev[8];
#pragma unroll
    for (int ct = 0; ct < 8; ++ct) {
        int n = w * 128 + ct * 16 + l15;
        wf[ct]  = Wf[n];
        bev[ct] = be[n];
    }
#pragma unroll
    for (int rt = 0; rt < 4; ++rt) {
#pragma unroll
        for (int reg = 0; reg < 4; ++reg) {
            int ml = rt * 16 + q * 4 + reg;          // local row (C/D: row=q*4+reg)
            int b  = (m0 + ml) / P_;
            const float* adp = att_dec + (size_t)b * A_ + w * 128 + l15;
            float p = 0.f;
#pragma unroll
            for (int ct = 0; ct < 8; ++ct) {
                float h = acc[rt][ct][reg] + bev[ct] + adp[ct * 16];
                p = fmaf(fmaxf(h, 0.f), wf[ct], p);
            }
#pragma unroll
            for (int off = 8; off > 0; off >>= 1)
                p += __shfl_down(p, off, 16);
            if (l15 == 0) sred[w][ml] = p;
        }
    }
    __syncthreads();
    if (t < 64)
        att[m0 + t] = sred[0][t] + sred[1][t] + sred[2][t] + sred[3][t];
}

// ---------------------------------------------------------------------------
// k_out: softmax over P then weighted feature sum. grid (B_, 2), block 256;
// each block does e-slice of 1024 (thread = one float4 column).
// ---------------------------------------------------------------------------
__global__ __launch_bounds__(256) void k_out(const float* __restrict__ enc,
                                             const float* __restrict__ att,
                                             float* __restrict__ out) {
    int b = blockIdx.x, t = threadIdx.x;
    __shared__ float sw[P_];
    __shared__ float red[8];

    float v = (t < P_) ? att[b * P_ + t] : -1e30f;
    float m = v;
#pragma unroll
    for (int off = 32; off > 0; off >>= 1)
        m = fmaxf(m, __shfl_down(m, off, 64));
    int wid = t >> 6;
    if ((t & 63) == 0) red[wid] = m;
    __syncthreads();
    m = fmaxf(fmaxf(red[0], red[1]), fmaxf(red[2], red[3]));

    float ev = (t < P_) ? __expf(v - m) : 0.f;
    float s = ev;
#pragma unroll
    for (int off = 32; off > 0; off >>= 1)
        s += __shfl_down(s, off, 64);
    if ((t & 63) == 0) red[4 + wid] = s;
    __syncthreads();
    s = red[4] + red[5] + red[6] + red[7];
    if (t < P_) sw[t] = ev / s;
    __syncthreads();

    const int e0 = blockIdx.y * 1024 + t * 4;
    const float* ep = enc + (size_t)b * P_ * E_ + e0;
    f32x4 acc = {0.f, 0.f, 0.f, 0.f};
#pragma unroll 4
    for (int p = 0; p < P_; ++p) {
        float4 qv = *(const float4*)(ep + (size_t)p * E_);
        float wgt = sw[p];
        acc[0] = fmaf(wgt, qv.x, acc[0]);
        acc[1] = fmaf(wgt, qv.y, acc[1]);
        acc[2] = fmaf(wgt, qv.z, acc[2]);
        acc[3] = fmaf(wgt, qv.w, acc[3]);
    }
    float* op = out + (size_t)b * E_ + e0;
    op[0] = acc[0]; op[1] = acc[1]; op[2] = acc[2]; op[3] = acc[3];
}

// ---------------------------------------------------------------------------
extern "C" void kernel_launch(void* const* d_in, const int* in_sizes, int n_in,
                              void* d_out, int out_size, void* d_ws, size_t ws_size,
                              hipStream_t stream) {
    const float* enc   = (const float*)d_in[0];  // [B,P,E]
    const float* dec   = (const float*)d_in[1];  // [B,WD]
    const float* W_enc = (const float*)d_in[2];  // [E,A]
    const float* b_enc = (const float*)d_in[3];  // [A]
    const float* W_dec = (const float*)d_in[4];  // [WD,A]
    const float* b_dec = (const float*)d_in[5];  // [A]
    const float* W_fin = (const float*)d_in[6];  // [A]
    // d_in[7] = b_fin: softmax-invariant -> unused.

    float* att_dec = (float*)d_ws;               // 256*512 f32
    float* att     = att_dec + B_ * A_;          // 50176 f32
    u16*   Wt      = (u16*)(att + M_);           // 512*2048 bf16 (16B-aligned)

    k_prep<<<dim3(E_ / 32, A_ / 32), 256, 0, stream>>>(W_enc, Wt);
    k_att_dec<<<B_, 512, 0, stream>>>(dec, W_dec, b_dec, att_dec);
    k_logits<<<M_ / 64, 256, 0, stream>>>(enc, Wt, b_enc, W_fin, att_dec, att);
    k_out<<<dim3(B_, 2), 256, 0, stream>>>(enc, att, (float*)d_out);
}

// Round 4
// 870.378 us; speedup vs baseline: 3.1358x; 1.0267x over previous
//
#include <hip/hip_runtime.h>

// Shapes: B=256, P=196, ENC=2048, WORD=512, ATT=512
#define B_   256
#define P_   196
#define E_   2048
#define WD_  512
#define A_   512
#define M_   (B_ * P_)   // 50176 = 784 * 64

typedef __bf16 bf16x8 __attribute__((ext_vector_type(8)));
typedef float  f32x4  __attribute__((ext_vector_type(4)));

using u16 = unsigned short;
using u32 = unsigned int;

__device__ inline u16 f2bf(float f) {  // RNE
    u32 u; __builtin_memcpy(&u, &f, 4);
    u += 0x7FFFu + ((u >> 16) & 1u); return (u16)(u >> 16);
}

// ---------------------------------------------------------------------------
// k_prep: W_enc fp32 [E][A] -> Wt bf16 [A][E] (transpose + convert).
// ---------------------------------------------------------------------------
__global__ __launch_bounds__(256) void k_prep(const float* __restrict__ We,
                                              u16* __restrict__ Wt) {
    __shared__ float tile[32][33];
    const int tx = threadIdx.x & 31, ty = threadIdx.x >> 5;
    const int k0 = blockIdx.x * 32, n0 = blockIdx.y * 32;
#pragma unroll
    for (int i = 0; i < 4; ++i)
        tile[ty + i * 8][tx] = We[(size_t)(k0 + ty + i * 8) * A_ + n0 + tx];
    __syncthreads();
#pragma unroll
    for (int i = 0; i < 4; ++i)
        Wt[(size_t)(n0 + ty + i * 8) * E_ + k0 + tx] = f2bf(tile[tx][ty + i * 8]);
}

// ---------------------------------------------------------------------------
// k_att_dec: att_dec[b][a] = dot(dec[b,:], Wd[:,a]) + bd[a]
// ---------------------------------------------------------------------------
__global__ __launch_bounds__(512) void k_att_dec(const float* __restrict__ dec,
                                                 const float* __restrict__ Wd,
                                                 const float* __restrict__ bd,
                                                 float* __restrict__ att_dec) {
    int b = blockIdx.x, a = threadIdx.x;
    __shared__ float sd[WD_];
    sd[a] = dec[b * WD_ + a];
    __syncthreads();
    float acc = bd[a];
#pragma unroll 8
    for (int e = 0; e < WD_; ++e)
        acc = fmaf(sd[e], Wd[e * A_ + a], acc);
    att_dec[b * A_ + a] = acc;
}

// ---------------------------------------------------------------------------
// k_logits v2: att[m] = sum_n relu(enc[m,:].W_enc[:,n] + be[n] + att_dec[b][n]) * Wf[n]
//
// Block 512 = 8 waves. M-tile 64 x N=512, BK=32, mfma_f32_16x16x32_bf16.
// Wave w owns cols [w*64, w*64+64) -> acc[4 rt][4 ct] (64 VGPR).
// * B: NO LDS (zero intra-block reuse) — global->VGPR, prefetch depth 1,
//   served from L2 (Wt = 2 MB, XCD-resident).
// * A: LDS double-buffered in MFMA fragment order (2 x 4 KB), fp32 loads
//   register-prefetched depth 2, converted to bf16 at ds_write time. Every
//   outstanding load at the __syncthreads drain is >= 1 full iteration old,
//   so the barrier costs ~HBM-BW only (no latency exposure).
// ---------------------------------------------------------------------------
__global__ __launch_bounds__(512, 2) void k_logits(
        const float* __restrict__ enc, const u16* __restrict__ Wt,
        const float* __restrict__ be, const float* __restrict__ Wf,
        const float* __restrict__ att_dec, float* __restrict__ att) {
    __shared__ bf16x8 sA[2][256];    // 2 x 4 KB, frag order: [rt*64 + lane]
    __shared__ float  sred[8][64];   // 2 KB

    const int t   = threadIdx.x;
    const int w   = t >> 6;          // wave 0..7
    const int L   = t & 63;
    const int l15 = L & 15;
    const int q   = L >> 4;          // 0..3
    const int m0  = blockIdx.x * 64;

    const f32x4 zero = {0.f, 0.f, 0.f, 0.f};
    f32x4 acc[4][4];
#pragma unroll
    for (int rt = 0; rt < 4; ++rt)
#pragma unroll
        for (int ct = 0; ct < 4; ++ct) acc[rt][ct] = zero;

    // --- A staging mapping: thread t stages half-slot (s = t>>1, h = t&1).
    // Slot s holds frag (rt = s>>6, lane sL = s&63): row rt*16 + (sL&15),
    // k-range within chunk: (sL>>4)*8 .. +7; half h covers 4 fp32 (16 B).
    const int s    = t >> 1, h = t & 1;
    const int srt  = s >> 6;
    const int sL   = s & 63;
    const float* ap = enc + (size_t)(m0 + srt * 16 + (sL & 15)) * E_
                          + (sL >> 4) * 8 + h * 4;
    u32* slds = (u32*)&sA[0][s] + h * 2;                 // buf0 dest (uint2)
    u32* slds1 = (u32*)&sA[1][s] + h * 2;                // buf1 dest

    // --- B per-lane base: Wt[(w*64 + ct*16 + l15)][k0 + q*8]
    const u16* bp = Wt + (size_t)(w * 64 + l15) * E_ + q * 8;
    const size_t bstep = (size_t)16 * E_;                // ct stride (rows)

    // --- prologue: bcur=B(0); A(0)->buf0; aN1=A(1) in regs ---
    uint4 bcur[4], bnxt[4];
#pragma unroll
    for (int ct = 0; ct < 4; ++ct)
        bcur[ct] = *(const uint4*)(bp + ct * bstep);
    float4 aN1 = *(const float4*)(ap);                   // A(0)
    float4 aN2 = *(const float4*)(ap + 32);              // A(1)
    {
        u32 lo = (u32)f2bf(aN1.x) | ((u32)f2bf(aN1.y) << 16);
        u32 hi = (u32)f2bf(aN1.z) | ((u32)f2bf(aN1.w) << 16);
        slds[0] = lo; slds[1] = hi;
    }
    aN1 = aN2;                                           // now A(1)
    __syncthreads();

    for (int k = 0; k < 64; ++k) {
        const int buf = k & 1;
        // A fragments for chunk k
        bf16x8 af[4];
#pragma unroll
        for (int rt = 0; rt < 4; ++rt) af[rt] = sA[buf][rt * 64 + L];

        // prefetch: A(k+2) and B(k+1) (clamped; dup-loads harmless)
        const int kA = (k + 2 < 64) ? k + 2 : 63;
        const int kB = (k + 1 < 64) ? k + 1 : 63;
        aN2 = *(const float4*)(ap + (size_t)kA * 32);
#pragma unroll
        for (int ct = 0; ct < 4; ++ct)
            bnxt[ct] = *(const uint4*)(bp + ct * bstep + (size_t)kB * 32);

        // MFMA: 16 per wave
#pragma unroll
        for (int ct = 0; ct < 4; ++ct) {
            bf16x8 bv; __builtin_memcpy(&bv, &bcur[ct], 16);
#pragma unroll
            for (int rt = 0; rt < 4; ++rt)
                acc[rt][ct] = __builtin_amdgcn_mfma_f32_16x16x32_bf16(
                    af[rt], bv, acc[rt][ct], 0, 0, 0);
        }

        // write A(k+1) -> other buffer (aN1 issued >= 1 iter ago)
        {
            u32 lo = (u32)f2bf(aN1.x) | ((u32)f2bf(aN1.y) << 16);
            u32 hi = (u32)f2bf(aN1.z) | ((u32)f2bf(aN1.w) << 16);
            u32* d = buf ? slds : slds1;
            d[0] = lo; d[1] = hi;
        }
        aN1 = aN2;
#pragma unroll
        for (int ct = 0; ct < 4; ++ct) bcur[ct] = bnxt[ct];
        __syncthreads();
    }

    // --- epilogue: relu(acc + be + att_dec) . Wf, reduce over n ---
    float wf[4], bev[4];
#pragma unroll
    for (int ct = 0; ct < 4; ++ct) {
        int n = w * 64 + ct * 16 + l15;
        wf[ct]  = Wf[n];
        bev[ct] = be[n];
    }
#pragma unroll
    for (int rt = 0; rt < 4; ++rt) {
#pragma unroll
        for (int reg = 0; reg < 4; ++reg) {
            int ml = rt * 16 + q * 4 + reg;              // C/D: row = q*4+reg
            int b  = (m0 + ml) / P_;
            const float* adp = att_dec + (size_t)b * A_ + w * 64 + l15;
            float p = 0.f;
#pragma unroll
            for (int ct = 0; ct < 4; ++ct) {
                float hx = acc[rt][ct][reg] + bev[ct] + adp[ct * 16];
                p = fmaf(fmaxf(hx, 0.f), wf[ct], p);
            }
#pragma unroll
            for (int off = 8; off > 0; off >>= 1)
                p += __shfl_down(p, off, 16);
            if (l15 == 0) sred[w][ml] = p;
        }
    }
    __syncthreads();
    if (t < 64) {
        float r = 0.f;
#pragma unroll
        for (int ww = 0; ww < 8; ++ww) r += sred[ww][t];
        att[m0 + t] = r;
    }
}

// ---------------------------------------------------------------------------
// k_out v2: softmax over P then weighted feature sum.
// grid (B_, 8), block 256. Each block: e-slice of 256 floats; p-range split
// across 4 thread-groups (tq) -> 4 independent load chains; combine in LDS.
// ---------------------------------------------------------------------------
__global__ __launch_bounds__(256) void k_out(const float* __restrict__ enc,
                                             const float* __restrict__ att,
                                             float* __restrict__ out) {
    int b = blockIdx.x, t = threadIdx.x;
    __shared__ float sw[P_];
    __shared__ float red[8];
    __shared__ f32x4 spart[4][64];

    float v = (t < P_) ? att[b * P_ + t] : -1e30f;
    float m = v;
#pragma unroll
    for (int off = 32; off > 0; off >>= 1)
        m = fmaxf(m, __shfl_down(m, off, 64));
    int wid = t >> 6;
    if ((t & 63) == 0) red[wid] = m;
    __syncthreads();
    m = fmaxf(fmaxf(red[0], red[1]), fmaxf(red[2], red[3]));

    float ev = (t < P_) ? __expf(v - m) : 0.f;
    float ssum = ev;
#pragma unroll
    for (int off = 32; off > 0; off >>= 1)
        ssum += __shfl_down(ssum, off, 64);
    if ((t & 63) == 0) red[4 + wid] = ssum;
    __syncthreads();
    ssum = red[4] + red[5] + red[6] + red[7];
    if (t < P_) sw[t] = ev / ssum;
    __syncthreads();

    const int tq = t >> 6, lane = t & 63;
    const int e0 = blockIdx.y * 256 + lane * 4;
    const float* ep = enc + (size_t)b * P_ * E_ + e0;
    f32x4 acc = {0.f, 0.f, 0.f, 0.f};
    const int p0 = tq * 49;                               // 196 = 4*49
#pragma unroll 7
    for (int i = 0; i < 49; ++i) {
        int p = p0 + i;
        float4 qv = *(const float4*)(ep + (size_t)p * E_);
        float wgt = sw[p];
        acc[0] = fmaf(wgt, qv.x, acc[0]);
        acc[1] = fmaf(wgt, qv.y, acc[1]);
        acc[2] = fmaf(wgt, qv.z, acc[2]);
        acc[3] = fmaf(wgt, qv.w, acc[3]);
    }
    spart[tq][lane] = acc;
    __syncthreads();
    if (tq == 0) {
        f32x4 r = spart[0][lane];
#pragma unroll
        for (int g = 1; g < 4; ++g) {
            f32x4 x = spart[g][lane];
            r[0] += x[0]; r[1] += x[1]; r[2] += x[2]; r[3] += x[3];
        }
        float* op = out + (size_t)b * E_ + e0;
        op[0] = r[0]; op[1] = r[1]; op[2] = r[2]; op[3] = r[3];
    }
}

// ---------------------------------------------------------------------------
extern "C" void kernel_launch(void* const* d_in, const int* in_sizes, int n_in,
                              void* d_out, int out_size, void* d_ws, size_t ws_size,
                              hipStream_t stream) {
    const float* enc   = (const float*)d_in[0];  // [B,P,E]
    const float* dec   = (const float*)d_in[1];  // [B,WD]
    const float* W_enc = (const float*)d_in[2];  // [E,A]
    const float* b_enc = (const float*)d_in[3];  // [A]
    const float* W_dec = (const float*)d_in[4];  // [WD,A]
    const float* b_dec = (const float*)d_in[5];  // [A]
    const float* W_fin = (const float*)d_in[6];  // [A]
    // d_in[7] = b_fin: softmax-invariant -> unused.

    float* att_dec = (float*)d_ws;               // 256*512 f32
    float* att     = att_dec + B_ * A_;          // 50176 f32
    u16*   Wt      = (u16*)(att + M_);           // 512*2048 bf16

    k_prep<<<dim3(E_ / 32, A_ / 32), 256, 0, stream>>>(W_enc, Wt);
    k_att_dec<<<B_, 512, 0, stream>>>(dec, W_dec, b_dec, att_dec);
    k_logits<<<M_ / 64, 512, 0, stream>>>(enc, Wt, b_enc, W_fin, att_dec, att);
    k_out<<<dim3(B_, 8), 256, 0, stream>>>(enc, att, (float*)d_out);
}